// Round 1
// baseline (1028.307 us; speedup 1.0000x reference)
//
#include <hip/hip_runtime.h>
#include <hip/hip_bf16.h>
#include <cstdint>
#include <cstddef>

typedef short bf16x8 __attribute__((ext_vector_type(8)));
typedef float f32x4 __attribute__((ext_vector_type(4)));

static __device__ __forceinline__ unsigned short f2bf(float f) {
    union { float f; uint32_t u; } c; c.f = f;
    uint32_t r = c.u + 0x7FFFu + ((c.u >> 16) & 1u);
    return (unsigned short)(r >> 16);
}

static __device__ __forceinline__ float fast_tanh(float x) {
    // exact: tanh(x) = 1 - 2/(exp(2x)+1); saturates correctly at +-inf
    float e = __expf(2.0f * x);
    return 1.0f - 2.0f / (e + 1.0f);
}

static __device__ __forceinline__ float softplus_f(float x) {
    return fmaxf(x, 0.0f) + log1pf(__expf(-fabsf(x)));
}

// ---------------- f32 -> bf16 conversion, 5 segments in one launch ----------
__global__ __launch_bounds__(256) void k_convert(
    const float* __restrict__ s0, const float* __restrict__ s1,
    const float* __restrict__ s2, const float* __restrict__ s3,
    const float* __restrict__ s4,
    unsigned short* __restrict__ d0, unsigned short* __restrict__ d1,
    unsigned short* __restrict__ d2, unsigned short* __restrict__ d3,
    unsigned short* __restrict__ d4,
    int n0, int n1, int n2, int n3, int n4)
{
    int i = blockIdx.x * 256 + threadIdx.x; // float4 index
    int c0 = n0 >> 2, c1 = c0 + (n1 >> 2), c2 = c1 + (n2 >> 2),
        c3 = c2 + (n3 >> 2), c4 = c3 + (n4 >> 2);
    if (i >= c4) return;
    const float* s; unsigned short* d; int j;
    if (i < c0)      { s = s0; d = d0; j = i; }
    else if (i < c1) { s = s1; d = d1; j = i - c0; }
    else if (i < c2) { s = s2; d = d2; j = i - c1; }
    else if (i < c3) { s = s3; d = d3; j = i - c2; }
    else             { s = s4; d = d4; j = i - c3; }
    float4 v = reinterpret_cast<const float4*>(s)[j];
    ushort4 o;
    o.x = f2bf(v.x); o.y = f2bf(v.y); o.z = f2bf(v.z); o.w = f2bf(v.w);
    reinterpret_cast<ushort4*>(d)[j] = o;
}

// ---------------- projection GEMM: out[m,f] = sum_d A[m,d]*W[f,d] + bias[f] --
// K = 512 fixed. Block: 256 thr (4 waves), tile 32(M) x 128(N).
__global__ __launch_bounds__(256) void k_proj(
    const unsigned short* __restrict__ A,   // [M][512] bf16
    const unsigned short* __restrict__ W,   // [1024][512] bf16
    const float* __restrict__ bias,         // [1024]
    float* __restrict__ out)                // [M][1024] f32
{
    __shared__ unsigned short As[32 * 512];
    const int tid = threadIdx.x;
    const int m0 = blockIdx.x * 32;
    const int c0 = blockIdx.y * 128;
    {
        int row = tid >> 3;                       // 8 threads per row
        const unsigned short* src = A + (size_t)(m0 + row) * 512;
        unsigned int base = row * 1024;           // bytes
        unsigned int sw = (row & 7) << 4;
        #pragma unroll
        for (int c = 0; c < 8; ++c) {
            int col = (tid & 7) * 8 + c * 64;
            bf16x8 v = *reinterpret_cast<const bf16x8*>(src + col);
            *reinterpret_cast<bf16x8*>(
                reinterpret_cast<char*>(As) + ((base + col * 2) ^ sw)) = v;
        }
    }
    __syncthreads();
    const int w = tid >> 6, l = tid & 63;
    const int lr = l & 15, lkb = (l >> 4) * 8;
    f32x4 acc[2][2] = {};
    const int colbase = c0 + w * 32;
    const unsigned short* Wb = W + (size_t)(colbase + lr) * 512 + lkb;
    const unsigned int sw = (lr & 7) << 4;
    for (int ks = 0; ks < 16; ++ks) {
        unsigned int kb = (ks * 32 + lkb) * 2;
        bf16x8 a0 = *reinterpret_cast<const bf16x8*>(
            reinterpret_cast<const char*>(As) + ((lr * 1024 + kb) ^ sw));
        bf16x8 a1 = *reinterpret_cast<const bf16x8*>(
            reinterpret_cast<const char*>(As) + (((16 + lr) * 1024 + kb) ^ sw));
        #pragma unroll
        for (int nf = 0; nf < 2; ++nf) {
            bf16x8 b = *reinterpret_cast<const bf16x8*>(Wb + nf * 16 * 512 + ks * 32);
            acc[0][nf] = __builtin_amdgcn_mfma_f32_16x16x32_bf16(a0, b, acc[0][nf], 0, 0, 0);
            acc[1][nf] = __builtin_amdgcn_mfma_f32_16x16x32_bf16(a1, b, acc[1][nf], 0, 0, 0);
        }
    }
    const int qr = (l >> 4) * 4;
    #pragma unroll
    for (int nf = 0; nf < 2; ++nf) {
        int col = colbase + nf * 16 + lr;
        float bv = bias[col];
        #pragma unroll
        for (int mf = 0; mf < 2; ++mf)
            #pragma unroll
            for (int r = 0; r < 4; ++r)
                out[(size_t)(m0 + mf * 16 + qr + r) * 1024 + col] = acc[mf][nf][r] + bv;
    }
}

// ---------------- fused joint kernel ----------------------------------------
// Block: 512 thr (8 waves), 32 rows of (b,t,u), full V=1024 (128 cols/wave).
// A = tanh(enc_row + dec_row) staged bf16 in LDS (XOR-swizzled), K-loop 32x32,
// W_fc read per-fragment from global (L2-resident 2MB), then in-register
// blank/log-softmax epilogue with cross-wave LDS reduction.
__global__ __launch_bounds__(512, 2) void k_main(
    const float* __restrict__ enc,            // [1600][1024] f32
    const float* __restrict__ dec,            // [320][1024] f32
    const unsigned short* __restrict__ Wfc,   // [1024][1024] bf16
    const float* __restrict__ bfc,            // [1024]
    float* __restrict__ out)                  // [128000][1024] f32
{
    __shared__ unsigned short As[32 * 1024];
    __shared__ float red[32][8];
    __shared__ float l0sh[32];
    const int tid = threadIdx.x;
    const int r0 = blockIdx.x * 32;
    {
        int row = tid >> 4;                       // 16 threads per row
        int rg = r0 + row;
        int bt = rg / 80;                         // b*400 + t
        int u = rg - bt * 80;
        int b = bt / 400;
        const float* ep = enc + (size_t)bt * 1024;
        const float* dp = dec + (size_t)(b * 80 + u) * 1024;
        unsigned int base = row * 2048;           // bytes
        unsigned int sw = (row & 7) << 4;
        #pragma unroll
        for (int c = 0; c < 8; ++c) {
            int col = (tid & 15) * 8 + c * 128;
            float4 e0 = *reinterpret_cast<const float4*>(ep + col);
            float4 e1 = *reinterpret_cast<const float4*>(ep + col + 4);
            float4 f0 = *reinterpret_cast<const float4*>(dp + col);
            float4 f1 = *reinterpret_cast<const float4*>(dp + col + 4);
            union { unsigned short h[8]; bf16x8 v; } pk;
            pk.h[0] = f2bf(fast_tanh(e0.x + f0.x));
            pk.h[1] = f2bf(fast_tanh(e0.y + f0.y));
            pk.h[2] = f2bf(fast_tanh(e0.z + f0.z));
            pk.h[3] = f2bf(fast_tanh(e0.w + f0.w));
            pk.h[4] = f2bf(fast_tanh(e1.x + f1.x));
            pk.h[5] = f2bf(fast_tanh(e1.y + f1.y));
            pk.h[6] = f2bf(fast_tanh(e1.z + f1.z));
            pk.h[7] = f2bf(fast_tanh(e1.w + f1.w));
            *reinterpret_cast<bf16x8*>(
                reinterpret_cast<char*>(As) + ((base + col * 2) ^ sw)) = pk.v;
        }
    }
    __syncthreads();
    const int w = tid >> 6, l = tid & 63;
    const int lr = l & 15, lkb = (l >> 4) * 8;
    f32x4 acc[2][8] = {};
    const unsigned short* Wb = Wfc + (size_t)(w * 128 + lr) * 1024 + lkb;
    const unsigned int sw = (lr & 7) << 4;
    for (int ks = 0; ks < 32; ++ks) {
        unsigned int kb = (ks * 32 + lkb) * 2;
        bf16x8 a0 = *reinterpret_cast<const bf16x8*>(
            reinterpret_cast<const char*>(As) + ((lr * 2048 + kb) ^ sw));
        bf16x8 a1 = *reinterpret_cast<const bf16x8*>(
            reinterpret_cast<const char*>(As) + (((16 + lr) * 2048 + kb) ^ sw));
        #pragma unroll
        for (int nf = 0; nf < 8; ++nf) {
            bf16x8 b = *reinterpret_cast<const bf16x8*>(Wb + nf * 16 * 1024 + ks * 32);
            acc[0][nf] = __builtin_amdgcn_mfma_f32_16x16x32_bf16(a0, b, acc[0][nf], 0, 0, 0);
            acc[1][nf] = __builtin_amdgcn_mfma_f32_16x16x32_bf16(a1, b, acc[1][nf], 0, 0, 0);
        }
    }
    // bias
    #pragma unroll
    for (int nf = 0; nf < 8; ++nf) {
        float bv = bfc[w * 128 + nf * 16 + lr];
        #pragma unroll
        for (int mf = 0; mf < 2; ++mf)
            #pragma unroll
            for (int r = 0; r < 4; ++r)
                acc[mf][nf][r] += bv;
    }
    // C layout: col = lane&15, row = (lane>>4)*4 + reg  (within 16x16 frag)
    const int q = l >> 4;
    const bool excl = (w == 0 && lr == 0);      // this lane's nf=0 value is col 0 (blank)
    if (excl) {
        #pragma unroll
        for (int mf = 0; mf < 2; ++mf)
            #pragma unroll
            for (int r = 0; r < 4; ++r)
                l0sh[mf * 16 + q * 4 + r] = acc[mf][0][r];
    }
    // per-row max over cols 1..1023
    float Mrow[2][4];
    #pragma unroll
    for (int mf = 0; mf < 2; ++mf)
        #pragma unroll
        for (int r = 0; r < 4; ++r) {
            float m = -3.0e38f;
            #pragma unroll
            for (int nf = 0; nf < 8; ++nf)
                if (!(excl && nf == 0)) m = fmaxf(m, acc[mf][nf][r]);
            #pragma unroll
            for (int s = 1; s < 16; s <<= 1)
                m = fmaxf(m, __shfl_xor(m, s, 16));
            if (lr == 0) red[mf * 16 + q * 4 + r][w] = m;
        }
    __syncthreads();
    #pragma unroll
    for (int mf = 0; mf < 2; ++mf)
        #pragma unroll
        for (int r = 0; r < 4; ++r) {
            int row = mf * 16 + q * 4 + r;
            float m = red[row][0];
            #pragma unroll
            for (int j = 1; j < 8; ++j) m = fmaxf(m, red[row][j]);
            Mrow[mf][r] = m;
        }
    __syncthreads();
    // per-row sum of exp over cols 1..1023
    #pragma unroll
    for (int mf = 0; mf < 2; ++mf)
        #pragma unroll
        for (int r = 0; r < 4; ++r) {
            float s = 0.0f;
            #pragma unroll
            for (int nf = 0; nf < 8; ++nf)
                if (!(excl && nf == 0)) s += __expf(acc[mf][nf][r] - Mrow[mf][r]);
            #pragma unroll
            for (int sh = 1; sh < 16; sh <<= 1)
                s += __shfl_xor(s, sh, 16);
            if (lr == 0) red[mf * 16 + q * 4 + r][w] = s;
        }
    __syncthreads();
    #pragma unroll
    for (int mf = 0; mf < 2; ++mf)
        #pragma unroll
        for (int r = 0; r < 4; ++r) {
            int row = mf * 16 + q * 4 + r;
            float s = red[row][0];
            #pragma unroll
            for (int j = 1; j < 8; ++j) s += red[row][j];
            float lse = Mrow[mf][r] + __logf(s);
            float l0 = l0sh[row];
            float lnb = -softplus_f(l0);          // log_sigmoid(-blank)
            float* op = out + (size_t)(r0 + row) * 1024;
            #pragma unroll
            for (int nf = 0; nf < 8; ++nf) {
                int col = w * 128 + nf * 16 + lr;
                float val = (col == 0) ? (-softplus_f(-l0))
                                       : (acc[mf][nf][r] - lse + lnb);
                op[col] = val;
            }
        }
}

extern "C" void kernel_launch(void* const* d_in, const int* in_sizes, int n_in,
                              void* d_out, int out_size, void* d_ws, size_t ws_size,
                              hipStream_t stream)
{
    const float* encoder = (const float*)d_in[0]; // [4,400,512]
    const float* decoder = (const float*)d_in[1]; // [4,80,512]
    const float* W_enc   = (const float*)d_in[2]; // [1024,512]
    const float* b_enc   = (const float*)d_in[3]; // [1024]
    const float* W_dec   = (const float*)d_in[4]; // [1024,512]
    const float* b_dec   = (const float*)d_in[5]; // [1024]
    const float* W_fc    = (const float*)d_in[6]; // [1024,1024]
    const float* b_fc    = (const float*)d_in[7]; // [1024]
    float* out = (float*)d_out;

    char* ws = (char*)d_ws;
    float*          enc_f  = (float*)(ws);                  // 1600*1024 f32
    float*          dec_f  = (float*)(ws + 6553600);        // 320*1024 f32
    unsigned short* Wfc_h  = (unsigned short*)(ws + 7864320);   // 1024*1024 bf16
    unsigned short* Wenc_h = (unsigned short*)(ws + 9961472);   // 1024*512 bf16
    unsigned short* Wdec_h = (unsigned short*)(ws + 11010048);  // 1024*512 bf16
    unsigned short* encI_h = (unsigned short*)(ws + 12058624);  // 1600*512 bf16
    unsigned short* decI_h = (unsigned short*)(ws + 13697024);  // 320*512 bf16

    const int nEnc = 4 * 400 * 512, nDec = 4 * 80 * 512;
    const int nWe = 1024 * 512, nWd = 1024 * 512, nWf = 1024 * 1024;
    const int totalF4 = (nEnc + nDec + nWe + nWd + nWf) >> 2;
    k_convert<<<(totalF4 + 255) / 256, 256, 0, stream>>>(
        encoder, decoder, W_enc, W_dec, W_fc,
        encI_h, decI_h, Wenc_h, Wdec_h, Wfc_h,
        nEnc, nDec, nWe, nWd, nWf);

    k_proj<<<dim3(1600 / 32, 8), 256, 0, stream>>>(encI_h, Wenc_h, b_enc, enc_f);
    k_proj<<<dim3(320 / 32, 8), 256, 0, stream>>>(decI_h, Wdec_h, b_dec, dec_f);

    k_main<<<4000, 512, 0, stream>>>(enc_f, dec_f, Wfc_h, b_fc, out);
}

// Round 2
// 675.591 us; speedup vs baseline: 1.5221x; 1.5221x over previous
//
#include <hip/hip_runtime.h>
#include <hip/hip_bf16.h>
#include <cstdint>
#include <cstddef>

typedef short bf16x8 __attribute__((ext_vector_type(8)));
typedef float f32x4 __attribute__((ext_vector_type(4)));

static __device__ __forceinline__ unsigned short f2bf(float f) {
    union { float f; uint32_t u; } c; c.f = f;
    uint32_t r = c.u + 0x7FFFu + ((c.u >> 16) & 1u);
    return (unsigned short)(r >> 16);
}

static __device__ __forceinline__ float fast_tanh(float x) {
    float e = __expf(2.0f * x);
    return 1.0f - 2.0f / (e + 1.0f);
}

static __device__ __forceinline__ float softplus_f(float x) {
    return fmaxf(x, 0.0f) + log1pf(__expf(-fabsf(x)));
}

// XOR swizzle: involution, key = addr bits 7-9 -> XOR into bits 4-6.
static __device__ __forceinline__ unsigned swz(unsigned a) {
    return a ^ (((a >> 7) & 7u) << 4);
}

#define GLOAD_LDS16(g, l) \
    __builtin_amdgcn_global_load_lds((const __attribute__((address_space(1))) void*)(g), \
                                     (__attribute__((address_space(3))) void*)(l), 16, 0, 0)

// ---------------- f32 -> bf16 conversion, 5 segments in one launch ----------
__global__ __launch_bounds__(256) void k_convert(
    const float* __restrict__ s0, const float* __restrict__ s1,
    const float* __restrict__ s2, const float* __restrict__ s3,
    const float* __restrict__ s4,
    unsigned short* __restrict__ d0, unsigned short* __restrict__ d1,
    unsigned short* __restrict__ d2, unsigned short* __restrict__ d3,
    unsigned short* __restrict__ d4,
    int n0, int n1, int n2, int n3, int n4)
{
    int i = blockIdx.x * 256 + threadIdx.x; // float4 index
    int c0 = n0 >> 2, c1 = c0 + (n1 >> 2), c2 = c1 + (n2 >> 2),
        c3 = c2 + (n3 >> 2), c4 = c3 + (n4 >> 2);
    if (i >= c4) return;
    const float* s; unsigned short* d; int j;
    if (i < c0)      { s = s0; d = d0; j = i; }
    else if (i < c1) { s = s1; d = d1; j = i - c0; }
    else if (i < c2) { s = s2; d = d2; j = i - c1; }
    else if (i < c3) { s = s3; d = d3; j = i - c2; }
    else             { s = s4; d = d4; j = i - c3; }
    float4 v = reinterpret_cast<const float4*>(s)[j];
    ushort4 o;
    o.x = f2bf(v.x); o.y = f2bf(v.y); o.z = f2bf(v.z); o.w = f2bf(v.w);
    reinterpret_cast<ushort4*>(d)[j] = o;
}

// ---------------- projection GEMM: out[m,f] = sum_d A[m,d]*W[f,d] + bias[f] --
__global__ __launch_bounds__(256) void k_proj(
    const unsigned short* __restrict__ A,   // [M][512] bf16
    const unsigned short* __restrict__ W,   // [1024][512] bf16
    const float* __restrict__ bias,         // [1024]
    float* __restrict__ out)                // [M][1024] f32
{
    __shared__ unsigned short As[32 * 512];
    const int tid = threadIdx.x;
    const int m0 = blockIdx.x * 32;
    const int c0 = blockIdx.y * 128;
    {
        int row = tid >> 3;
        const unsigned short* src = A + (size_t)(m0 + row) * 512;
        unsigned int base = row * 1024;
        unsigned int sw = (row & 7) << 4;
        #pragma unroll
        for (int c = 0; c < 8; ++c) {
            int col = (tid & 7) * 8 + c * 64;
            bf16x8 v = *reinterpret_cast<const bf16x8*>(src + col);
            *reinterpret_cast<bf16x8*>(
                reinterpret_cast<char*>(As) + ((base + col * 2) ^ sw)) = v;
        }
    }
    __syncthreads();
    const int w = tid >> 6, l = tid & 63;
    const int lr = l & 15, lkb = (l >> 4) * 8;
    f32x4 acc[2][2] = {};
    const int colbase = c0 + w * 32;
    const unsigned short* Wb = W + (size_t)(colbase + lr) * 512 + lkb;
    const unsigned int sw = (lr & 7) << 4;
    for (int ks = 0; ks < 16; ++ks) {
        unsigned int kb = (ks * 32 + lkb) * 2;
        bf16x8 a0 = *reinterpret_cast<const bf16x8*>(
            reinterpret_cast<const char*>(As) + ((lr * 1024 + kb) ^ sw));
        bf16x8 a1 = *reinterpret_cast<const bf16x8*>(
            reinterpret_cast<const char*>(As) + (((16 + lr) * 1024 + kb) ^ sw));
        #pragma unroll
        for (int nf = 0; nf < 2; ++nf) {
            bf16x8 b = *reinterpret_cast<const bf16x8*>(Wb + nf * 16 * 512 + ks * 32);
            acc[0][nf] = __builtin_amdgcn_mfma_f32_16x16x32_bf16(a0, b, acc[0][nf], 0, 0, 0);
            acc[1][nf] = __builtin_amdgcn_mfma_f32_16x16x32_bf16(a1, b, acc[1][nf], 0, 0, 0);
        }
    }
    const int qr = (l >> 4) * 4;
    #pragma unroll
    for (int nf = 0; nf < 2; ++nf) {
        int col = colbase + nf * 16 + lr;
        float bv = bias[col];
        #pragma unroll
        for (int mf = 0; mf < 2; ++mf)
            #pragma unroll
            for (int r = 0; r < 4; ++r)
                out[(size_t)(m0 + mf * 16 + qr + r) * 1024 + col] = acc[mf][nf][r] + bv;
    }
}

// ---------------- fused joint kernel ----------------------------------------
// Block: 512 thr (8 waves). Tile: 64 rows x full V=1024, K=1024 in 32 steps
// of BK=32. Per step: Bs[1024][32] bf16 (64KB) staged via global_load_lds
// (linear dest, inverse-swizzled source); As[64][32] bf16 (4KB) computed
// (tanh(enc+dec)) and ds_written swizzled. Double-buffered, one barrier/step.
// Per wave: 64 rows x 128 cols -> acc[4][8] f32x4. Epilogue: blank/log-softmax
// in-register + cross-wave LDS reduce, single write of final log-probs.
__global__ __launch_bounds__(512, 2) void k_main(
    const float* __restrict__ enc,            // [1600][1024] f32
    const float* __restrict__ dec,            // [320][1024] f32
    const unsigned short* __restrict__ Wfc,   // [1024][1024] bf16
    const float* __restrict__ bfc,            // [1024]
    float* __restrict__ out)                  // [128000][1024] f32
{
    extern __shared__ char smem[];
    char* Bs0 = smem;
    char* Bs1 = smem + 65536;
    char* As0 = smem + 131072;
    char* As1 = smem + 135168;
    float* red  = (float*)(smem + 139264);   // [64][8]
    float* l0sh = (float*)(smem + 141312);   // [64]

    const int tid = threadIdx.x;
    const int w = tid >> 6, l = tid & 63;
    const int lr = l & 15, q = l >> 4;
    const int r0 = blockIdx.x * 64;

    // ---- per-thread A staging setup: row = tid>>3, 4 k-elems at (tid&7)*4
    const int arow = tid >> 3;
    const float4* epv;
    const float4* dpv;
    {
        int m = r0 + arow;
        int bt = m / 80;
        int u  = m - bt * 80;
        int b  = bt / 400;
        epv = (const float4*)(enc + (size_t)bt * 1024 + (tid & 7) * 4);
        dpv = (const float4*)(dec + (size_t)(b * 80 + u) * 1024 + (tid & 7) * 4);
    }
    const unsigned awoff = swz((unsigned)(arow * 64 + (tid & 7) * 8));

    // ---- per-thread B staging setup (linear LDS dest, pre-swizzled source)
    // dest(linear) = w*8192 + i*1024 + l*16 ; logical = swz(dest)
    const unsigned loff  = ((unsigned)l * 16u) ^ ((((unsigned)l >> 3) & 7u) << 4);
    const unsigned vbase = (unsigned)w * 128u + (loff >> 6);
    const unsigned kbe   = (loff & 63u) >> 1;          // element offset in k
    const unsigned short* gB = Wfc + (size_t)vbase * 1024 + kbe;

    // ---- fragment read offsets (constant per thread)
    unsigned aoff[4], boff[8];
    #pragma unroll
    for (int mf = 0; mf < 4; ++mf)
        aoff[mf] = swz((unsigned)(((mf * 16 + lr) << 6) | (q << 4)));
    #pragma unroll
    for (int nf = 0; nf < 8; ++nf)
        boff[nf] = swz((unsigned)(((w * 128 + nf * 16 + lr) << 6) | (q << 4)));

    f32x4 acc[4][8] = {};

    // ---- prologue: stage step 0 into buffer 0
    {
        #pragma unroll
        for (int i = 0; i < 8; ++i)
            GLOAD_LDS16(gB + i * 16 * 1024, Bs0 + w * 8192 + i * 1024);
        float4 e0 = epv[0], d0 = dpv[0];
        union { unsigned short h[4]; uint2 u; } pk;
        pk.h[0] = f2bf(fast_tanh(e0.x + d0.x));
        pk.h[1] = f2bf(fast_tanh(e0.y + d0.y));
        pk.h[2] = f2bf(fast_tanh(e0.z + d0.z));
        pk.h[3] = f2bf(fast_tanh(e0.w + d0.w));
        *(uint2*)(As0 + awoff) = pk.u;
    }
    __syncthreads();

    char* Bcur = Bs0; char* Bnxt = Bs1;
    char* Acur = As0; char* Anxt = As1;

    for (int ks = 0; ks < 32; ++ks) {
        const bool pre = (ks < 31);
        float4 e0, d0;
        if (pre) {
            // issue next-step loads early: enc/dec f32 (for tanh) first,
            // then the 8 global_load_lds for B (hide under MFMA below)
            e0 = epv[(ks + 1) * 8];
            d0 = dpv[(ks + 1) * 8];
            const unsigned short* g = gB + (ks + 1) * 32;
            #pragma unroll
            for (int i = 0; i < 8; ++i)
                GLOAD_LDS16(g + i * 16 * 1024, Bnxt + w * 8192 + i * 1024);
        }
        // MFMA cluster on current buffers
        bf16x8 a[4];
        #pragma unroll
        for (int mf = 0; mf < 4; ++mf)
            a[mf] = *(const bf16x8*)(Acur + aoff[mf]);
        #pragma unroll
        for (int nf = 0; nf < 8; ++nf) {
            bf16x8 b = *(const bf16x8*)(Bcur + boff[nf]);
            #pragma unroll
            for (int mf = 0; mf < 4; ++mf)
                acc[mf][nf] = __builtin_amdgcn_mfma_f32_16x16x32_bf16(a[mf], b, acc[mf][nf], 0, 0, 0);
        }
        if (pre) {
            union { unsigned short h[4]; uint2 u; } pk;
            pk.h[0] = f2bf(fast_tanh(e0.x + d0.x));
            pk.h[1] = f2bf(fast_tanh(e0.y + d0.y));
            pk.h[2] = f2bf(fast_tanh(e0.z + d0.z));
            pk.h[3] = f2bf(fast_tanh(e0.w + d0.w));
            *(uint2*)(Anxt + awoff) = pk.u;
        }
        __syncthreads();
        char* t;
        t = Bcur; Bcur = Bnxt; Bnxt = t;
        t = Acur; Acur = Anxt; Anxt = t;
    }

    // ---- epilogue: bias, blank, log-softmax over cols 1..1023
    #pragma unroll
    for (int nf = 0; nf < 8; ++nf) {
        float bv = bfc[w * 128 + nf * 16 + lr];
        #pragma unroll
        for (int mf = 0; mf < 4; ++mf)
            #pragma unroll
            for (int r = 0; r < 4; ++r)
                acc[mf][nf][r] += bv;
    }
    const bool excl = (w == 0 && lr == 0);   // this lane's nf=0 value is col 0
    if (excl) {
        #pragma unroll
        for (int mf = 0; mf < 4; ++mf)
            #pragma unroll
            for (int r = 0; r < 4; ++r)
                l0sh[mf * 16 + q * 4 + r] = acc[mf][0][r];
    }
    // per-row max over cols 1..1023
    float Mrow[4][4];
    #pragma unroll
    for (int mf = 0; mf < 4; ++mf)
        #pragma unroll
        for (int r = 0; r < 4; ++r) {
            float m = -3.0e38f;
            #pragma unroll
            for (int nf = 0; nf < 8; ++nf)
                if (!(excl && nf == 0)) m = fmaxf(m, acc[mf][nf][r]);
            #pragma unroll
            for (int s = 1; s < 16; s <<= 1)
                m = fmaxf(m, __shfl_xor(m, s, 16));
            if (lr == 0) red[(mf * 16 + q * 4 + r) * 8 + w] = m;
        }
    __syncthreads();
    #pragma unroll
    for (int mf = 0; mf < 4; ++mf)
        #pragma unroll
        for (int r = 0; r < 4; ++r) {
            int row = mf * 16 + q * 4 + r;
            float m = red[row * 8 + 0];
            #pragma unroll
            for (int j = 1; j < 8; ++j) m = fmaxf(m, red[row * 8 + j]);
            Mrow[mf][r] = m;
        }
    __syncthreads();
    // per-row sum of exp over cols 1..1023
    #pragma unroll
    for (int mf = 0; mf < 4; ++mf)
        #pragma unroll
        for (int r = 0; r < 4; ++r) {
            float s = 0.0f;
            #pragma unroll
            for (int nf = 0; nf < 8; ++nf)
                if (!(excl && nf == 0)) s += __expf(acc[mf][nf][r] - Mrow[mf][r]);
            #pragma unroll
            for (int sh = 1; sh < 16; sh <<= 1)
                s += __shfl_xor(s, sh, 16);
            if (lr == 0) red[(mf * 16 + q * 4 + r) * 8 + w] = s;
        }
    __syncthreads();
    #pragma unroll
    for (int mf = 0; mf < 4; ++mf)
        #pragma unroll
        for (int r = 0; r < 4; ++r) {
            int row = mf * 16 + q * 4 + r;
            float s = red[row * 8 + 0];
            #pragma unroll
            for (int j = 1; j < 8; ++j) s += red[row * 8 + j];
            float lse = Mrow[mf][r] + __logf(s);
            float l0 = l0sh[row];
            float lnb = -softplus_f(l0);          // log_sigmoid(-blank)
            float* op = out + (size_t)(r0 + row) * 1024;
            #pragma unroll
            for (int nf = 0; nf < 8; ++nf) {
                int col = w * 128 + nf * 16 + lr;
                float val = (col == 0) ? (-softplus_f(-l0))
                                       : (acc[mf][nf][r] - lse + lnb);
                op[col] = val;
            }
        }
}

extern "C" void kernel_launch(void* const* d_in, const int* in_sizes, int n_in,
                              void* d_out, int out_size, void* d_ws, size_t ws_size,
                              hipStream_t stream)
{
    const float* encoder = (const float*)d_in[0]; // [4,400,512]
    const float* decoder = (const float*)d_in[1]; // [4,80,512]
    const float* W_enc   = (const float*)d_in[2]; // [1024,512]
    const float* b_enc   = (const float*)d_in[3]; // [1024]
    const float* W_dec   = (const float*)d_in[4]; // [1024,512]
    const float* b_dec   = (const float*)d_in[5]; // [1024]
    const float* W_fc    = (const float*)d_in[6]; // [1024,1024]
    const float* b_fc    = (const float*)d_in[7]; // [1024]
    float* out = (float*)d_out;

    char* ws = (char*)d_ws;
    float*          enc_f  = (float*)(ws);                  // 1600*1024 f32
    float*          dec_f  = (float*)(ws + 6553600);        // 320*1024 f32
    unsigned short* Wfc_h  = (unsigned short*)(ws + 7864320);   // 1024*1024 bf16
    unsigned short* Wenc_h = (unsigned short*)(ws + 9961472);   // 1024*512 bf16
    unsigned short* Wdec_h = (unsigned short*)(ws + 11010048);  // 1024*512 bf16
    unsigned short* encI_h = (unsigned short*)(ws + 12058624);  // 1600*512 bf16
    unsigned short* decI_h = (unsigned short*)(ws + 13697024);  // 320*512 bf16

    const int nEnc = 4 * 400 * 512, nDec = 4 * 80 * 512;
    const int nWe = 1024 * 512, nWd = 1024 * 512, nWf = 1024 * 1024;
    const int totalF4 = (nEnc + nDec + nWe + nWd + nWf) >> 2;
    k_convert<<<(totalF4 + 255) / 256, 256, 0, stream>>>(
        encoder, decoder, W_enc, W_dec, W_fc,
        encI_h, decI_h, Wenc_h, Wdec_h, Wfc_h,
        nEnc, nDec, nWe, nWd, nWf);

    k_proj<<<dim3(1600 / 32, 8), 256, 0, stream>>>(encI_h, Wenc_h, b_enc, enc_f);
    k_proj<<<dim3(320 / 32, 8), 256, 0, stream>>>(decI_h, Wdec_h, b_dec, dec_f);

    const int SMEM_BYTES = 141568;
    hipFuncSetAttribute(reinterpret_cast<const void*>(k_main),
                        hipFuncAttributeMaxDynamicSharedMemorySize, SMEM_BYTES);
    k_main<<<2000, 512, SMEM_BYTES, stream>>>(enc_f, dec_f, Wfc_h, b_fc, out);
}